// Round 12
// baseline (98.630 us; speedup 1.0000x reference)
//
#include <hip/hip_runtime.h>
#include <hip/hip_bf16.h>

// Problem constants
constexpr int NPAT = 8192;     // B*PH*PW = 8*32*32
constexpr int NPER = 1024;     // coords period: summary/h1/bias/wgt repeat every 1024

typedef __attribute__((ext_vector_type(8))) short short8v;   // 8 bf16
typedef __attribute__((ext_vector_type(4))) float f32x4;

#define GLOAD16(g, l) __builtin_amdgcn_global_load_lds( \
    (const __attribute__((address_space(1))) void*)(g), \
    (__attribute__((address_space(3))) void*)(l), 16, 0, 0)

__device__ inline short bf16s(float f) {
    __hip_bfloat16 h = __float2bfloat16(f);
    return *reinterpret_cast<short*>(&h);
}
__device__ inline unsigned short bf16u(float f) {
    __hip_bfloat16 h = __float2bfloat16(f);
    return *reinterpret_cast<unsigned short*>(&h);
}
__device__ inline float bf2f(short s) {
    return __uint_as_float(((unsigned int)(unsigned short)s) << 16);
}

// ---------------------------------------------------------------------------
// K-PREP: weight prep only.
//   [0,512):   wn_w2 -> w2t [2][4096][256] bf16 (transposed)
//   [512,576): conv_w -> cwt_g (pre-swizzled)
//   [576,960): w1t / w2bt for k_mlp_mfma
__global__ __launch_bounds__(256) void k_prep(const float* __restrict__ w2,
                                              const float* __restrict__ cw,
                                              const float* __restrict__ wn_w1,
                                              const float* __restrict__ bn_w1,
                                              const float* __restrict__ bn_w2,
                                              __hip_bfloat16* __restrict__ w2t,
                                              __hip_bfloat16* __restrict__ cwt_g,
                                              __hip_bfloat16* __restrict__ w1t,
                                              __hip_bfloat16* __restrict__ w2bt) {
    __shared__ float tile[64][65];
    int bid = blockIdx.x;
    int t = threadIdx.x;
    if (bid < 512) {
        int b = bid >> 8;
        int rem = bid & 255;
        int kt = rem >> 6, nt = rem & 63;
        const float* src = w2 + (size_t)b * 256 * 4096 + (size_t)(kt * 64) * 4096 + nt * 64;
        for (int it = 0; it < 16; ++it) {
            int idx = t + it * 256;
            int r = idx >> 6, c = idx & 63;
            tile[r][c] = src[(size_t)r * 4096 + c];
        }
        __syncthreads();
        __hip_bfloat16* dst = w2t + (size_t)b * 4096 * 256 + (size_t)(nt * 64) * 256 + kt * 64;
        for (int it = 0; it < 16; ++it) {
            int idx = t + it * 256;
            int rr = idx >> 6, cc = idx & 63;
            dst[rr * 256 + cc] = __float2bfloat16(tile[cc][rr]);
        }
    } else if (bid < 576) {
        int idx = (bid - 512) * 256 + t;
        int oc = idx >> 6, cc = idx & 63;
        float v = cw[cc * 256 + oc];
        int el = oc * 64 + (((cc >> 3) ^ (oc & 7)) << 3) + (cc & 7);
        cwt_g[el] = __float2bfloat16(v);
    } else {
        int idx = (bid - 576) * 256 + t;
        if (idx < 2 * 512 * 64) {
            int b = idx >> 15; int r = idx & 32767; int n = r >> 6; int k = r & 63;
            const float* src = (n < 256) ? wn_w1 : bn_w1;
            float v = src[((size_t)b * 64 + k) * 256 + (n & 255)];
            w1t[idx] = __float2bfloat16(v);
        } else {
            int j = idx - 2 * 512 * 64;
            int b = j >> 14; int r = j & 16383; int c = r >> 8; int k = r & 255;
            float v = bn_w2[((size_t)b * 256 + k) * 64 + c];
            w2bt[j] = __float2bfloat16(v);
        }
    }
}

// ---------------------------------------------------------------------------
// K3 (MFMA): both hyper-blocks, 1024 distinct patches. 64 blocks, 32 patches
// each. Summary MLP computed inline.
__global__ __launch_bounds__(256) void k_mlp_mfma(const float* __restrict__ pixpos,
                                                  const float* __restrict__ pw1,
                                                  const float* __restrict__ pb1,
                                                  const float* __restrict__ pw2,
                                                  const float* __restrict__ pb2,
                                                  const __hip_bfloat16* __restrict__ w1t_all,
                                                  const float* __restrict__ wn_b1,
                                                  const float* __restrict__ bn_b1,
                                                  const __hip_bfloat16* __restrict__ w2bt_all,
                                                  const float* __restrict__ bn_b2,
                                                  __hip_bfloat16* __restrict__ h1_all,
                                                  float* __restrict__ bias_all) {
    __shared__ short st[32 * 64];
    __shared__ short hb[32 * 256];
    __shared__ float hs[32][257];
    int t = threadIdx.x;
    int l = t & 63, w = t >> 6;
    int bi = blockIdx.x;
    int i = bi >> 5;
    int m0 = (bi & 31) * 32;
    int lrow = l & 15, hi = l >> 4;

    const __hip_bfloat16* w1t = w1t_all + (size_t)i * 512 * 64;
    const __hip_bfloat16* w2bt = w2bt_all + (size_t)i * 64 * 256;
    const float* b1w = wn_b1 + i * 256;
    const float* b1b = bn_b1 + i * 256;
    const float* b2b = bn_b2 + i * 64;
    __hip_bfloat16* h1out = h1_all + (size_t)i * NPER * 256;
    float* biasout = bias_all + (size_t)i * NPER * 64;

    // ---- inline summary: hidden silu for 32 patches (t = hidden index k)
    {
        float w1a = pw1[t], w1b_ = pw1[256 + t], b1v = pb1[t];
        for (int m = 0; m < 32; ++m) {
            int n = m0 + m;
            float cy = (float)(n >> 5) * (1.f / 31.f);
            float cx = (float)(n & 31) * (1.f / 31.f);
            float v = cy * w1a + cx * w1b_ + b1v;
            hs[m][t] = v / (1.f + __expf(-v));
        }
    }
    __syncthreads();
    {
        int c = t & 63, mg = t >> 6;
        float pm = 0.f;
        for (int p = 0; p < 16; ++p) pm += pixpos[p * 64 + c];
        pm *= (1.f / 16.f);
        float accs[8];
        #pragma unroll
        for (int j = 0; j < 8; ++j) accs[j] = pb2[c];
        for (int k = 0; k < 256; ++k) {
            float wv = pw2[k * 64 + c];
            #pragma unroll
            for (int j = 0; j < 8; ++j) accs[j] += hs[mg * 8 + j][k] * wv;
        }
        int q = c >> 3;
        #pragma unroll
        for (int j = 0; j < 8; ++j) {
            int m = mg * 8 + j;
            st[m * 64 + ((q ^ (m & 7)) << 3) + (c & 7)] = bf16s(accs[j] + pm);
        }
    }
    __syncthreads();

    f32x4 acc[8][2] = {};
    for (int ks = 0; ks < 2; ++ks) {
        short8v a[8], bb[2];
        for (int ii = 0; ii < 8; ++ii) {
            int n = w * 128 + ii * 16 + lrow;
            a[ii] = *(const short8v*)&w1t[(size_t)n * 64 + ks * 32 + hi * 8];
        }
        for (int j = 0; j < 2; ++j) {
            int m = j * 16 + lrow;
            int kk = ks * 4 + hi;
            bb[j] = *(const short8v*)((const char*)st + m * 128 + ((kk ^ (m & 7)) << 4));
        }
        for (int ii = 0; ii < 8; ++ii)
            for (int j = 0; j < 2; ++j)
                acc[ii][j] = __builtin_amdgcn_mfma_f32_16x16x32_bf16(a[ii], bb[j], acc[ii][j], 0, 0, 0);
    }
    if (w < 2) {
        for (int ii = 0; ii < 8; ++ii) {
            int n0_ = w * 128 + ii * 16 + hi * 4;
            float4 bw = *(const float4*)&b1w[n0_];
            float bwa[4] = {bw.x, bw.y, bw.z, bw.w};
            for (int j = 0; j < 2; ++j) {
                union { unsigned short s[4]; unsigned long long u; } pk;
                for (int r = 0; r < 4; ++r) {
                    float z = acc[ii][j][r] + bwa[r];
                    pk.s[r] = bf16u(z / (1.f + __expf(-z)));
                }
                int m = m0 + j * 16 + lrow;
                *(unsigned long long*)&h1out[(size_t)m * 256 + n0_] = pk.u;
            }
        }
    } else {
        for (int ii = 0; ii < 8; ++ii) {
            int nb0 = (w - 2) * 128 + ii * 16 + hi * 4;
            float4 bw = *(const float4*)&b1b[nb0];
            float bwa[4] = {bw.x, bw.y, bw.z, bw.w};
            for (int j = 0; j < 2; ++j) {
                union { unsigned short s[4]; unsigned long long u; } pk;
                for (int r = 0; r < 4; ++r) {
                    float z = acc[ii][j][r] + bwa[r];
                    pk.s[r] = bf16u(z / (1.f + __expf(-z)));
                }
                int mloc = j * 16 + lrow;
                int qq = nb0 >> 3;
                *(unsigned long long*)((char*)hb + mloc * 512 +
                                       ((qq ^ (mloc & 7)) << 4) + ((nb0 & 7) << 1)) = pk.u;
            }
        }
    }
    __syncthreads();

    f32x4 acc2[2] = {};
    for (int ks = 0; ks < 8; ++ks) {
        short8v a2 = *(const short8v*)&w2bt[(size_t)(w * 16 + lrow) * 256 + ks * 32 + hi * 8];
        for (int j = 0; j < 2; ++j) {
            int ml = j * 16 + lrow;
            int kk = ks * 4 + hi;
            short8v b2f = *(const short8v*)((const char*)hb + ml * 512 + ((kk ^ (ml & 7)) << 4));
            acc2[j] = __builtin_amdgcn_mfma_f32_16x16x32_bf16(a2, b2f, acc2[j], 0, 0, 0);
        }
    }
    {
        int c0 = w * 16 + hi * 4;
        float4 bv = *(const float4*)&b2b[c0];
        for (int j = 0; j < 2; ++j) {
            int m = m0 + j * 16 + lrow;
            float4 o;
            o.x = acc2[j][0] + bv.x; o.y = acc2[j][1] + bv.y;
            o.z = acc2[j][2] + bv.z; o.w = acc2[j][3] + bv.w;
            *(float4*)&biasout[(size_t)m * 64 + c0] = o;
        }
    }
}

// ---------------------------------------------------------------------------
// K-COMBO: blocks [0,512): wgt GEMM (MFMA-bound); blocks [512,1536): unfold
// extract x -> procb (memory-bound). Independent work, overlapped.
__global__ __launch_bounds__(256) void k_combo(const __hip_bfloat16* __restrict__ h1_all,
                                               const __hip_bfloat16* __restrict__ w2t_all,
                                               const float* __restrict__ b2_all,
                                               __hip_bfloat16* __restrict__ wgt_all,
                                               const float* __restrict__ x,
                                               __hip_bfloat16* __restrict__ proc) {
    __shared__ __align__(16) char smem[34816];
    int t = threadIdx.x;
    if (blockIdx.x < 512) {
        // ---- wgt GEMM: M=1024, N=4096, K=256, both hyper-blocks
        short* sm0 = (short*)smem;
        short* sm1 = sm0 + 128 * 68;
        int l = t & 63, w = t >> 6;
        int i = blockIdx.x >> 8;
        int bid8 = blockIdx.x & 255;
        int mt = bid8 & 7, nt = bid8 >> 3;
        int m0 = mt << 7, n0 = nt << 7;
        int wr = w >> 1, wc = w & 1;
        int lrow = l & 15, hi = l >> 4;

        const __hip_bfloat16* h1 = h1_all + (size_t)i * NPER * 256;
        const __hip_bfloat16* w2t = w2t_all + (size_t)i * 4096 * 256;
        const float* b2 = b2_all + (size_t)i * 4096;
        __hip_bfloat16* wgt = wgt_all + ((size_t)i << 22);

        f32x4 acc[4][4] = {};
        const char* gA = (const char*)(h1 + (size_t)m0 * 256);
        const char* gB = (const char*)(w2t + (size_t)n0 * 256);

        for (int ks = 0; ks < 4; ++ks) {
            int k0 = ks * 64;
            #pragma unroll
            for (int it = 0; it < 4; ++it) {
                int c = it * 256 + t;
                int row = c >> 3, q = c & 7;
                size_t goff = ((size_t)row * 256 + k0 + ((q ^ (row & 7)) << 3)) * 2;
                size_t ldst = (size_t)(it * 256 + w * 64) * 16;
                GLOAD16(gA + goff, (char*)sm0 + ldst);
                GLOAD16(gB + goff, (char*)sm1 + ldst);
            }
            __syncthreads();
            #pragma unroll
            for (int kk = 0; kk < 2; ++kk) {
                int kq = kk * 4 + hi;
                short8v a[4], b[4];
                #pragma unroll
                for (int fi = 0; fi < 4; ++fi) {
                    int row = wc * 64 + fi * 16 + lrow;
                    a[fi] = *(const short8v*)((const char*)sm1 + row * 128 + ((kq ^ (row & 7)) << 4));
                }
                #pragma unroll
                for (int fj = 0; fj < 4; ++fj) {
                    int row = wr * 64 + fj * 16 + lrow;
                    b[fj] = *(const short8v*)((const char*)sm0 + row * 128 + ((kq ^ (row & 7)) << 4));
                }
                #pragma unroll
                for (int fi = 0; fi < 4; ++fi)
                    #pragma unroll
                    for (int fj = 0; fj < 4; ++fj)
                        acc[fi][fj] = __builtin_amdgcn_mfma_f32_16x16x32_bf16(a[fi], b[fj], acc[fi][fj], 0, 0, 0);
            }
            __syncthreads();
        }

        short* epi = (short*)smem;
        #pragma unroll
        for (int fi = 0; fi < 4; ++fi) {
            int nl = wc * 64 + fi * 16 + hi * 4;
            float4 bv = *(const float4*)&b2[n0 + nl];
            float bva[4] = {bv.x, bv.y, bv.z, bv.w};
            #pragma unroll
            for (int fj = 0; fj < 4; ++fj) {
                int m = wr * 64 + fj * 16 + lrow;
                union { unsigned short s[4]; unsigned long long u; } pk;
                #pragma unroll
                for (int r = 0; r < 4; ++r)
                    pk.s[r] = bf16u(acc[fi][fj][r] + bva[r]);
                *(unsigned long long*)((char*)epi + (size_t)m * 272 + nl * 2) = pk.u;
            }
        }
        __syncthreads();
        #pragma unroll
        for (int pass = 0; pass < 8; ++pass) {
            int row = pass * 16 + (t >> 4);
            int c8 = (t & 15) * 8;
            uint4 v = *(const uint4*)((const char*)epi + (size_t)row * 272 + c8 * 2);
            *(uint4*)&wgt[(size_t)(m0 + row) * 4096 + n0 + c8] = v;
        }
    } else {
        // ---- extract: unfold x -> proc bf16
        float (*tile)[129] = (float(*)[129])smem;
        int bid2 = blockIdx.x - 512;
        int b = bid2 >> 7, h = bid2 & 127;
        for (int it = 0; it < 8; ++it) {
            int idx = it * 256 + t;
            int c = idx >> 5, w4 = (idx & 31) * 4;
            float4 v = *(const float4*)&x[(((size_t)b * 64 + c) * 128 + h) * 128 + w4];
            tile[c][w4] = v.x; tile[c][w4 + 1] = v.y;
            tile[c][w4 + 2] = v.z; tile[c][w4 + 3] = v.w;
        }
        __syncthreads();
        int ny = (h >> 2) * 32, py = h & 3;
        for (int it = 0; it < 16; ++it) {
            int pw = it * 8 + (t >> 5);
            int cc = (t & 31) * 2;
            int n = (b << 10) + ny + (pw >> 2);
            int p = (py << 2) + (pw & 3);
            unsigned int u = (unsigned int)bf16u(tile[cc][pw]) |
                             ((unsigned int)bf16u(tile[cc + 1][pw]) << 16);
            *(unsigned int*)(proc + ((size_t)n << 10) + (p << 6) + cc) = u;
        }
    }
}

// ---------------------------------------------------------------------------
// K-STRIP: fused bmm(x2) + conv + pixel shuffle (r10-proven version).
// Block = (b, gy, half): 16 patches, 512 threads (8 waves).
__global__ __launch_bounds__(512) void k_strip(const __hip_bfloat16* __restrict__ proc,
                                               const __hip_bfloat16* __restrict__ wgt_all,
                                               const float* __restrict__ bias_all,
                                               const float* __restrict__ ln_g,
                                               const float* __restrict__ ln_b,
                                               const __hip_bfloat16* __restrict__ cwt_g,
                                               const float* __restrict__ cb,
                                               float* __restrict__ out) {
    __shared__ short tk[256 * 64];    // 32 KB
    __shared__ short cwt[256 * 64];   // 32 KB
    __shared__ float cbl[256];
    int t = threadIdx.x;
    int l = t & 63, w8 = t >> 6;
    int bid = blockIdx.x;
    int half = bid & 1, gy = (bid >> 1) & 31, b = bid >> 6;
    int nbase = (b << 10) + (gy << 5) + (half << 4);

    // ---- stage conv weights (2048 chunks)
    for (int it = 0; it < 4; ++it) {
        int cid0 = it * 512 + w8 * 64;
        GLOAD16((const char*)cwt_g + ((size_t)(cid0 + l) << 4),
                (char*)cwt + ((size_t)cid0 << 4));
    }
    if (t < 256) cbl[t] = cb[t];
    // ---- stage token tile (2048 chunks), pre-swizzled global source
    {
        const char* psrc = (const char*)(proc + ((size_t)nbase << 10));
        for (int it = 0; it < 4; ++it) {
            int c = it * 512 + t;
            int r = c >> 3, q = c & 7;
            int wl = r & 63, py = r >> 6;
            int f = (py + (wl & 3) + (((wl >> 2) & 1) << 2)) & 7;
            int goff = ((wl >> 2) << 11) + (((py << 2) + (wl & 3)) << 7) + ((q ^ f) << 4);
            GLOAD16(psrc + goff, (char*)tk + ((size_t)(it * 512 + w8 * 64) << 4));
        }
    }
    __syncthreads();

    // ---- bmm: wave handles patches gxl = w8*2, w8*2+1
    {
        int p = l & 15, hi = l >> 4;
        for (int rnd = 0; rnd < 2; ++rnd) {
            const float* gbase = ln_g + rnd * 64;
            const float* bbase = ln_b + rnd * 64;
            float4 g0 = *(const float4*)&gbase[hi * 8];
            float4 g1 = *(const float4*)&gbase[hi * 8 + 4];
            float4 g2 = *(const float4*)&gbase[32 + hi * 8];
            float4 g3 = *(const float4*)&gbase[32 + hi * 8 + 4];
            float4 e0 = *(const float4*)&bbase[hi * 8];
            float4 e1 = *(const float4*)&bbase[hi * 8 + 4];
            float4 e2 = *(const float4*)&bbase[32 + hi * 8];
            float4 e3 = *(const float4*)&bbase[32 + hi * 8 + 4];
            float gA[8] = {g0.x, g0.y, g0.z, g0.w, g1.x, g1.y, g1.z, g1.w};
            float gB[8] = {g2.x, g2.y, g2.z, g2.w, g3.x, g3.y, g3.z, g3.w};
            float eA[8] = {e0.x, e0.y, e0.z, e0.w, e1.x, e1.y, e1.z, e1.w};
            float eB[8] = {e2.x, e2.y, e2.z, e2.w, e3.x, e3.y, e3.z, e3.w};
            #pragma unroll
            for (int gg = 0; gg < 2; ++gg) {
                int gxl = (w8 << 1) + gg;
                int nw = (gy << 5) + (half << 4) + gxl;
                const __hip_bfloat16* wrow = wgt_all + ((size_t)rnd << 22) + ((size_t)nw << 12);
                const float* brow = bias_all + ((size_t)rnd << 16) + ((size_t)nw << 6);
                int wl = (gxl << 2) + (p & 3);
                int py = p >> 2;
                int r = (py << 6) + wl;
                int f = (py + (p & 3) + ((gxl & 1) << 2)) & 7;
                char* trow = (char*)tk + r * 128;
                short8v aA = *(const short8v*)(trow + ((hi ^ f) << 4));
                short8v aB = *(const short8v*)(trow + (((4 + hi) ^ f) << 4));
                unsigned long long res[4];
                #pragma unroll
                for (int ib = 0; ib < 4; ++ib) {
                    int i0 = (ib << 4) + (hi << 2);
                    res[ib] = *(const unsigned long long*)(trow + (((i0 >> 3) ^ f) << 4) + ((i0 & 7) << 1));
                }
                float va[8], vb[8];
                float s = 0.f, s2 = 0.f;
                #pragma unroll
                for (int e = 0; e < 8; ++e) {
                    va[e] = bf2f(aA[e]); vb[e] = bf2f(aB[e]);
                    s += va[e] + vb[e];
                    s2 += va[e] * va[e] + vb[e] * vb[e];
                }
                s += __shfl_xor(s, 16); s2 += __shfl_xor(s2, 16);
                s += __shfl_xor(s, 32); s2 += __shfl_xor(s2, 32);
                float mean = s * (1.f / 64.f);
                float var = s2 * (1.f / 64.f) - mean * mean;
                float rinv = rsqrtf(var + 1e-5f);
                short8v bf0, bf1;
                #pragma unroll
                for (int e = 0; e < 8; ++e) {
                    bf0[e] = bf16s((va[e] - mean) * rinv * gA[e] + eA[e]);
                    bf1[e] = bf16s((vb[e] - mean) * rinv * gB[e] + eB[e]);
                }
                short8v af[4][2];
                #pragma unroll
                for (int ib = 0; ib < 4; ++ib) {
                    af[ib][0] = *(const short8v*)&wrow[((ib * 16 + p) << 6) + hi * 8];
                    af[ib][1] = *(const short8v*)&wrow[((ib * 16 + p) << 6) + 32 + hi * 8];
                }
                f32x4 acc[4] = {};
                #pragma unroll
                for (int ib = 0; ib < 4; ++ib) {
                    acc[ib] = __builtin_amdgcn_mfma_f32_16x16x32_bf16(af[ib][0], bf0, acc[ib], 0, 0, 0);
                    acc[ib] = __builtin_amdgcn_mfma_f32_16x16x32_bf16(af[ib][1], bf1, acc[ib], 0, 0, 0);
                }
                #pragma unroll
                for (int ib = 0; ib < 4; ++ib) {
                    int i0 = (ib << 4) + (hi << 2);
                    float4 bsv = *(const float4*)&brow[i0];
                    float ba[4] = {bsv.x, bsv.y, bsv.z, bsv.w};
                    union { unsigned short s[4]; unsigned long long u; } pk;
                    #pragma unroll
                    for (int rr2 = 0; rr2 < 4; ++rr2) {
                        float rv = bf2f((short)((res[ib] >> (16 * rr2)) & 0xffff));
                        pk.s[rr2] = bf16u(acc[ib][rr2] + ba[rr2] + rv);
                    }
                    *(unsigned long long*)(trow + (((i0 >> 3) ^ f) << 4) + ((i0 & 7) << 1)) = pk.u;
                }
            }
            __syncthreads();
        }
    }

    // ---- conv: wave w8 -> (py = w8>>1, oc-half wvo = w8&1); 2 oc sub-passes
    {
        int py = w8 >> 1, wvo = w8 & 1;
        int lrow = l & 15, lhi = l >> 4;
        int hh = (gy << 2) + py;
        #pragma unroll
        for (int ih = 0; ih < 2; ++ih) {
            f32x4 acc[4][4] = {};
            #pragma unroll
            for (int ks = 0; ks < 2; ++ks) {
                int q = (ks << 2) + lhi;
                short8v a[4], bb[4];
                #pragma unroll
                for (int i = 0; i < 4; ++i) {
                    int ocr = wvo * 128 + (ih * 4 + i) * 16 + lrow;
                    a[i] = *(const short8v*)((const char*)cwt + ocr * 128 + ((q ^ (ocr & 7)) << 4));
                }
                #pragma unroll
                for (int j = 0; j < 4; ++j) {
                    int wl = (j << 4) + lrow;
                    int rr = (py << 6) + wl;
                    int ff = (py + (wl & 3) + (((wl >> 2) & 1) << 2)) & 7;
                    bb[j] = *(const short8v*)((const char*)tk + rr * 128 + ((q ^ ff) << 4));
                }
                #pragma unroll
                for (int i = 0; i < 4; ++i)
                    #pragma unroll
                    for (int j = 0; j < 4; ++j)
                        acc[i][j] = __builtin_amdgcn_mfma_f32_16x16x32_bf16(a[i], bb[j], acc[i][j], 0, 0, 0);
            }
            #pragma unroll
            for (int i = 0; i < 4; ++i) {
                int oc4 = wvo * 128 + (ih * 4 + i) * 16 + lhi * 4;
                int c = oc4 >> 2;
                float cb0 = cbl[oc4], cb1 = cbl[oc4 + 1];
                float cb2 = cbl[oc4 + 2], cb3 = cbl[oc4 + 3];
                float* row0 = out + (((size_t)b * 64 + c) * 256 + 2 * hh) * 256;
                float* row1 = row0 + 256;
                #pragma unroll
                for (int j = 0; j < 4; ++j) {
                    int ww = (half << 6) + (j << 4) + lrow;
                    ((float2*)row0)[ww] = make_float2(acc[i][j][0] + cb0, acc[i][j][1] + cb1);
                    ((float2*)row1)[ww] = make_float2(acc[i][j][2] + cb2, acc[i][j][3] + cb3);
                }
            }
        }
    }
}

// ---------------------------------------------------------------------------
extern "C" void kernel_launch(void* const* d_in, const int* in_sizes, int n_in,
                              void* d_out, int out_size, void* d_ws, size_t ws_size,
                              hipStream_t stream) {
    const float* x      = (const float*)d_in[0];
    const float* pixpos = (const float*)d_in[1];
    const float* ppe_w1 = (const float*)d_in[2];
    const float* ppe_b1 = (const float*)d_in[3];
    const float* ppe_w2 = (const float*)d_in[4];
    const float* ppe_b2 = (const float*)d_in[5];
    const float* ln_g   = (const float*)d_in[6];
    const float* ln_b   = (const float*)d_in[7];
    const float* wn_w1  = (const float*)d_in[8];
    const float* wn_b1  = (const float*)d_in[9];
    const float* wn_w2  = (const float*)d_in[10];
    const float* wn_b2  = (const float*)d_in[11];
    const float* bn_w1  = (const float*)d_in[12];
    const float* bn_b1  = (const float*)d_in[13];
    const float* bn_w2  = (const float*)d_in[14];
    const float* bn_b2  = (const float*)d_in[15];
    const float* conv_w = (const float*)d_in[16];
    const float* conv_b = (const float*)d_in[17];
    float* out = (float*)d_out;

    char* wsb = (char*)d_ws;
    __hip_bfloat16* procb   = (__hip_bfloat16*)wsb; wsb += (size_t)NPAT * 1024 * 2;     // 16 MB
    __hip_bfloat16* wgt_all = (__hip_bfloat16*)wsb; wsb += (size_t)2 * NPER * 4096 * 2; // 16 MB
    __hip_bfloat16* h1      = (__hip_bfloat16*)wsb; wsb += (size_t)2 * NPER * 256 * 2;  //  1 MB
    __hip_bfloat16* w2t     = (__hip_bfloat16*)wsb; wsb += (size_t)2 * 4096 * 256 * 2;  //  4 MB
    float* bias             = (float*)wsb;          wsb += (size_t)2 * NPER * 64 * 4;   // 512 KB
    __hip_bfloat16* w1t     = (__hip_bfloat16*)wsb; wsb += (size_t)2 * 512 * 64 * 2;    // 128 KB
    __hip_bfloat16* w2bt    = (__hip_bfloat16*)wsb; wsb += (size_t)2 * 64 * 256 * 2;    //  64 KB
    __hip_bfloat16* cwt_g   = (__hip_bfloat16*)wsb;                                     //  32 KB

    k_prep<<<960, 256, 0, stream>>>(wn_w2, conv_w, wn_w1, bn_w1, bn_w2,
                                    w2t, cwt_g, w1t, w2bt);
    k_mlp_mfma<<<64, 256, 0, stream>>>(pixpos, ppe_w1, ppe_b1, ppe_w2, ppe_b2,
                                       w1t, wn_b1, bn_b1, w2bt, bn_b2, h1, bias);
    k_combo<<<1536, 256, 0, stream>>>(h1, w2t, wn_b2, wgt_all, x, procb);
    k_strip<<<512, 512, 0, stream>>>(procb, wgt_all, bias, ln_g, ln_b,
                                     cwt_g, conv_b, out);
}

// Round 13
// 85.767 us; speedup vs baseline: 1.1500x; 1.1500x over previous
//
#include <hip/hip_runtime.h>
#include <hip/hip_bf16.h>

// Problem constants
constexpr int NPAT = 8192;     // B*PH*PW = 8*32*32
constexpr int NPER = 1024;     // coords period: summary/h1/bias/wgt repeat every 1024

typedef __attribute__((ext_vector_type(8))) short short8v;   // 8 bf16
typedef __attribute__((ext_vector_type(4))) float f32x4;

#define GLOAD16(g, l) __builtin_amdgcn_global_load_lds( \
    (const __attribute__((address_space(1))) void*)(g), \
    (__attribute__((address_space(3))) void*)(l), 16, 0, 0)

__device__ inline short bf16s(float f) {
    __hip_bfloat16 h = __float2bfloat16(f);
    return *reinterpret_cast<short*>(&h);
}
__device__ inline unsigned short bf16u(float f) {
    __hip_bfloat16 h = __float2bfloat16(f);
    return *reinterpret_cast<unsigned short*>(&h);
}
__device__ inline float bf2f(short s) {
    return __uint_as_float(((unsigned int)(unsigned short)s) << 16);
}

// ---------------------------------------------------------------------------
// K-SETUP: block-range dispatch.
//   [0,1024):    unfold x -> proc bf16
//   [1024,1280): summary for 1024 distinct coords (4 patches/block)
//   [1280,2240): weight prep (w2t transpose, cwt swizzle, w1t/w2bt)
__global__ __launch_bounds__(256) void k_setup(const float* __restrict__ x,
                                               __hip_bfloat16* __restrict__ proc,
                                               const float* __restrict__ pixpos,
                                               const float* __restrict__ pw1,
                                               const float* __restrict__ pb1,
                                               const float* __restrict__ pw2,
                                               const float* __restrict__ pb2,
                                               __hip_bfloat16* __restrict__ summ,
                                               const float* __restrict__ w2,
                                               const float* __restrict__ cw,
                                               const float* __restrict__ wn_w1,
                                               const float* __restrict__ bn_w1,
                                               const float* __restrict__ bn_w2,
                                               __hip_bfloat16* __restrict__ w2t,
                                               __hip_bfloat16* __restrict__ cwt_g,
                                               __hip_bfloat16* __restrict__ w1t,
                                               __hip_bfloat16* __restrict__ w2bt) {
    __shared__ __align__(16) char smem[33024];
    int bid = blockIdx.x;
    int t = threadIdx.x;
    if (bid < 1024) {
        // ---- extract
        float (*tile)[129] = (float(*)[129])smem;
        int b = bid >> 7, h = bid & 127;
        for (int it = 0; it < 8; ++it) {
            int idx = it * 256 + t;
            int c = idx >> 5, w4 = (idx & 31) * 4;
            float4 v = *(const float4*)&x[(((size_t)b * 64 + c) * 128 + h) * 128 + w4];
            tile[c][w4] = v.x; tile[c][w4 + 1] = v.y;
            tile[c][w4 + 2] = v.z; tile[c][w4 + 3] = v.w;
        }
        __syncthreads();
        int ny = (h >> 2) * 32, py = h & 3;
        for (int it = 0; it < 16; ++it) {
            int pw = it * 8 + (t >> 5);
            int cc = (t & 31) * 2;
            int n = (b << 10) + ny + (pw >> 2);
            int p = (py << 2) + (pw & 3);
            unsigned int u = (unsigned int)bf16u(tile[cc][pw]) |
                             ((unsigned int)bf16u(tile[cc + 1][pw]) << 16);
            *(unsigned int*)(proc + ((size_t)n << 10) + (p << 6) + cc) = u;
        }
    } else if (bid < 1280) {
        // ---- summary: wave w handles distinct-coord patch n in [0,1024)
        float (*hs)[260] = (float(*)[260])smem;
        int l = t & 63, w = t >> 6;
        int n = (bid - 1024) * 4 + w;
        float cy = (float)(n >> 5) * (1.f / 31.f);
        float cx = (float)(n & 31) * (1.f / 31.f);
        for (int k4 = 0; k4 < 4; ++k4) {
            int k = k4 * 64 + l;
            float v = cy * pw1[k] + cx * pw1[256 + k] + pb1[k];
            hs[w][k] = v / (1.f + __expf(-v));
        }
        float acc = pb2[l];
        for (int k = 0; k < 256; ++k) acc += hs[w][k] * pw2[k * 64 + l];
        float pm = 0.f;
        for (int p = 0; p < 16; ++p) pm += pixpos[p * 64 + l];
        summ[(size_t)n * 64 + l] = __float2bfloat16(acc + pm * (1.f / 16.f));
    } else {
        int pb = bid - 1280;
        if (pb < 512) {
            float (*tile)[65] = (float(*)[65])smem;
            int b = pb >> 8;
            int rem = pb & 255;
            int kt = rem >> 6, nt = rem & 63;
            const float* src = w2 + (size_t)b * 256 * 4096 + (size_t)(kt * 64) * 4096 + nt * 64;
            for (int it = 0; it < 16; ++it) {
                int idx = t + it * 256;
                int r = idx >> 6, c = idx & 63;
                tile[r][c] = src[(size_t)r * 4096 + c];
            }
            __syncthreads();
            __hip_bfloat16* dst = w2t + (size_t)b * 4096 * 256 + (size_t)(nt * 64) * 256 + kt * 64;
            for (int it = 0; it < 16; ++it) {
                int idx = t + it * 256;
                int rr = idx >> 6, cc = idx & 63;
                dst[rr * 256 + cc] = __float2bfloat16(tile[cc][rr]);
            }
        } else if (pb < 576) {
            int idx = (pb - 512) * 256 + t;
            int oc = idx >> 6, cc = idx & 63;
            float v = cw[cc * 256 + oc];
            int el = oc * 64 + (((cc >> 3) ^ (oc & 7)) << 3) + (cc & 7);
            cwt_g[el] = __float2bfloat16(v);
        } else {
            int idx = (pb - 576) * 256 + t;
            if (idx < 2 * 512 * 64) {
                int b = idx >> 15; int r = idx & 32767; int n = r >> 6; int k = r & 63;
                const float* src = (n < 256) ? wn_w1 : bn_w1;
                float v = src[((size_t)b * 64 + k) * 256 + (n & 255)];
                w1t[idx] = __float2bfloat16(v);
            } else {
                int j = idx - 2 * 512 * 64;
                int b = j >> 14; int r = j & 16383; int c = r >> 8; int k = r & 255;
                float v = bn_w2[((size_t)b * 256 + k) * 64 + c];
                w2bt[j] = __float2bfloat16(v);
            }
        }
    }
}

// ---------------------------------------------------------------------------
// K3 (MFMA): both hyper-blocks, 1024 distinct patches. 64 blocks, 32 patches each.
__global__ __launch_bounds__(256) void k_mlp_mfma(const __hip_bfloat16* __restrict__ summary,
                                                  const __hip_bfloat16* __restrict__ w1t_all,
                                                  const float* __restrict__ wn_b1,
                                                  const float* __restrict__ bn_b1,
                                                  const __hip_bfloat16* __restrict__ w2bt_all,
                                                  const float* __restrict__ bn_b2,
                                                  __hip_bfloat16* __restrict__ h1_all,
                                                  float* __restrict__ bias_all) {
    __shared__ short st[32 * 64];
    __shared__ short hb[32 * 256];
    int t = threadIdx.x;
    int l = t & 63, w = t >> 6;
    int bi = blockIdx.x;
    int i = bi >> 5;
    int m0 = (bi & 31) * 32;
    int lrow = l & 15, hi = l >> 4;

    const __hip_bfloat16* w1t = w1t_all + (size_t)i * 512 * 64;
    const __hip_bfloat16* w2bt = w2bt_all + (size_t)i * 64 * 256;
    const float* b1w = wn_b1 + i * 256;
    const float* b1b = bn_b1 + i * 256;
    const float* b2b = bn_b2 + i * 64;
    __hip_bfloat16* h1out = h1_all + (size_t)i * NPER * 256;
    float* biasout = bias_all + (size_t)i * NPER * 64;

    {
        int chunk = w * 64 + l;
        int m = chunk >> 3, q = chunk & 7;
        int gq = q ^ (m & 7);
        GLOAD16((const char*)(summary + ((size_t)(m0 + m) << 6) + (gq << 3)),
                (char*)st + (size_t)(w * 64) * 16);
    }
    __syncthreads();

    f32x4 acc[8][2] = {};
    for (int ks = 0; ks < 2; ++ks) {
        short8v a[8], bb[2];
        for (int ii = 0; ii < 8; ++ii) {
            int n = w * 128 + ii * 16 + lrow;
            a[ii] = *(const short8v*)&w1t[(size_t)n * 64 + ks * 32 + hi * 8];
        }
        for (int j = 0; j < 2; ++j) {
            int m = j * 16 + lrow;
            int kk = ks * 4 + hi;
            bb[j] = *(const short8v*)((const char*)st + m * 128 + ((kk ^ (m & 7)) << 4));
        }
        for (int ii = 0; ii < 8; ++ii)
            for (int j = 0; j < 2; ++j)
                acc[ii][j] = __builtin_amdgcn_mfma_f32_16x16x32_bf16(a[ii], bb[j], acc[ii][j], 0, 0, 0);
    }
    if (w < 2) {
        for (int ii = 0; ii < 8; ++ii) {
            int n0_ = w * 128 + ii * 16 + hi * 4;
            float4 bw = *(const float4*)&b1w[n0_];
            float bwa[4] = {bw.x, bw.y, bw.z, bw.w};
            for (int j = 0; j < 2; ++j) {
                union { unsigned short s[4]; unsigned long long u; } pk;
                for (int r = 0; r < 4; ++r) {
                    float z = acc[ii][j][r] + bwa[r];
                    pk.s[r] = bf16u(z / (1.f + __expf(-z)));
                }
                int m = m0 + j * 16 + lrow;
                *(unsigned long long*)&h1out[(size_t)m * 256 + n0_] = pk.u;
            }
        }
    } else {
        for (int ii = 0; ii < 8; ++ii) {
            int nb0 = (w - 2) * 128 + ii * 16 + hi * 4;
            float4 bw = *(const float4*)&b1b[nb0];
            float bwa[4] = {bw.x, bw.y, bw.z, bw.w};
            for (int j = 0; j < 2; ++j) {
                union { unsigned short s[4]; unsigned long long u; } pk;
                for (int r = 0; r < 4; ++r) {
                    float z = acc[ii][j][r] + bwa[r];
                    pk.s[r] = bf16u(z / (1.f + __expf(-z)));
                }
                int mloc = j * 16 + lrow;
                int qq = nb0 >> 3;
                *(unsigned long long*)((char*)hb + mloc * 512 +
                                       ((qq ^ (mloc & 7)) << 4) + ((nb0 & 7) << 1)) = pk.u;
            }
        }
    }
    __syncthreads();

    f32x4 acc2[2] = {};
    for (int ks = 0; ks < 8; ++ks) {
        short8v a2 = *(const short8v*)&w2bt[(size_t)(w * 16 + lrow) * 256 + ks * 32 + hi * 8];
        for (int j = 0; j < 2; ++j) {
            int ml = j * 16 + lrow;
            int kk = ks * 4 + hi;
            short8v b2f = *(const short8v*)((const char*)hb + ml * 512 + ((kk ^ (ml & 7)) << 4));
            acc2[j] = __builtin_amdgcn_mfma_f32_16x16x32_bf16(a2, b2f, acc2[j], 0, 0, 0);
        }
    }
    {
        int c0 = w * 16 + hi * 4;
        float4 bv = *(const float4*)&b2b[c0];
        for (int j = 0; j < 2; ++j) {
            int m = m0 + j * 16 + lrow;
            float4 o;
            o.x = acc2[j][0] + bv.x; o.y = acc2[j][1] + bv.y;
            o.z = acc2[j][2] + bv.z; o.w = acc2[j][3] + bv.w;
            *(float4*)&biasout[(size_t)m * 64 + c0] = o;
        }
    }
}

// ---------------------------------------------------------------------------
// K4: wgt GEMM for BOTH hyper-blocks. M=1024, N=4096, K=256 each.
__global__ __launch_bounds__(256) void k_wgt_mfma(const __hip_bfloat16* __restrict__ h1_all,
                                                  const __hip_bfloat16* __restrict__ w2t_all,
                                                  const float* __restrict__ b2_all,
                                                  __hip_bfloat16* __restrict__ wgt_all) {
    __shared__ short sm[2][128 * 68];
    int t = threadIdx.x;
    int l = t & 63, w = t >> 6;
    int i = blockIdx.x >> 8;
    int bid8 = blockIdx.x & 255;
    int mt = bid8 & 7, nt = bid8 >> 3;
    int m0 = mt << 7, n0 = nt << 7;
    int wr = w >> 1, wc = w & 1;
    int lrow = l & 15, hi = l >> 4;

    const __hip_bfloat16* h1 = h1_all + (size_t)i * NPER * 256;
    const __hip_bfloat16* w2t = w2t_all + (size_t)i * 4096 * 256;
    const float* b2 = b2_all + (size_t)i * 4096;
    __hip_bfloat16* wgt = wgt_all + ((size_t)i << 22);

    f32x4 acc[4][4] = {};

    const char* gA = (const char*)(h1 + (size_t)m0 * 256);
    const char* gB = (const char*)(w2t + (size_t)n0 * 256);

    for (int ks = 0; ks < 4; ++ks) {
        int k0 = ks * 64;
        #pragma unroll
        for (int it = 0; it < 4; ++it) {
            int c = it * 256 + t;
            int row = c >> 3, q = c & 7;
            size_t goff = ((size_t)row * 256 + k0 + ((q ^ (row & 7)) << 3)) * 2;
            size_t ldst = (size_t)(it * 256 + w * 64) * 16;
            GLOAD16(gA + goff, (char*)sm[0] + ldst);
            GLOAD16(gB + goff, (char*)sm[1] + ldst);
        }
        __syncthreads();
        #pragma unroll
        for (int kk = 0; kk < 2; ++kk) {
            int kq = kk * 4 + hi;
            short8v a[4], b[4];
            #pragma unroll
            for (int fi = 0; fi < 4; ++fi) {
                int row = wc * 64 + fi * 16 + lrow;
                a[fi] = *(const short8v*)((const char*)sm[1] + row * 128 + ((kq ^ (row & 7)) << 4));
            }
            #pragma unroll
            for (int fj = 0; fj < 4; ++fj) {
                int row = wr * 64 + fj * 16 + lrow;
                b[fj] = *(const short8v*)((const char*)sm[0] + row * 128 + ((kq ^ (row & 7)) << 4));
            }
            #pragma unroll
            for (int fi = 0; fi < 4; ++fi)
                #pragma unroll
                for (int fj = 0; fj < 4; ++fj)
                    acc[fi][fj] = __builtin_amdgcn_mfma_f32_16x16x32_bf16(a[fi], b[fj], acc[fi][fj], 0, 0, 0);
        }
        __syncthreads();
    }

    short* epi = (short*)sm;
    #pragma unroll
    for (int fi = 0; fi < 4; ++fi) {
        int nl = wc * 64 + fi * 16 + hi * 4;
        float4 bv = *(const float4*)&b2[n0 + nl];
        float bva[4] = {bv.x, bv.y, bv.z, bv.w};
        #pragma unroll
        for (int fj = 0; fj < 4; ++fj) {
            int m = wr * 64 + fj * 16 + lrow;
            union { unsigned short s[4]; unsigned long long u; } pk;
            #pragma unroll
            for (int r = 0; r < 4; ++r)
                pk.s[r] = bf16u(acc[fi][fj][r] + bva[r]);
            *(unsigned long long*)((char*)epi + (size_t)m * 272 + nl * 2) = pk.u;
        }
    }
    __syncthreads();
    #pragma unroll
    for (int pass = 0; pass < 8; ++pass) {
        int row = pass * 16 + (t >> 4);
        int c8 = (t & 15) * 8;
        uint4 v = *(const uint4*)((const char*)epi + (size_t)row * 272 + c8 * 2);
        *(uint4*)&wgt[(size_t)(m0 + row) * 4096 + n0 + c8] = v;
    }
}

// ---------------------------------------------------------------------------
// K-STRIP: fused bmm(x2) + conv + pixel shuffle.
// Block = (b, gy, half): 16 patches, 512 threads (8 waves). Conv weights read
// directly from global cwt_g (L2-resident, pre-swizzled) — no LDS staging.
__global__ __launch_bounds__(512) void k_strip(const __hip_bfloat16* __restrict__ proc,
                                               const __hip_bfloat16* __restrict__ wgt_all,
                                               const float* __restrict__ bias_all,
                                               const float* __restrict__ ln_g,
                                               const float* __restrict__ ln_b,
                                               const __hip_bfloat16* __restrict__ cwt_g,
                                               const float* __restrict__ cb,
                                               float* __restrict__ out) {
    __shared__ short tk[256 * 64];    // 32 KB
    __shared__ float cbl[256];
    int t = threadIdx.x;
    int l = t & 63, w8 = t >> 6;
    int bid = blockIdx.x;
    int half = bid & 1, gy = (bid >> 1) & 31, b = bid >> 6;
    int nbase = (b << 10) + (gy << 5) + (half << 4);

    if (t < 256) cbl[t] = cb[t];
    // ---- stage token tile (2048 chunks), pre-swizzled global source
    {
        const char* psrc = (const char*)(proc + ((size_t)nbase << 10));
        for (int it = 0; it < 4; ++it) {
            int c = it * 512 + t;
            int r = c >> 3, q = c & 7;
            int wl = r & 63, py = r >> 6;
            int f = (py + (wl & 3) + (((wl >> 2) & 1) << 2)) & 7;
            int goff = ((wl >> 2) << 11) + (((py << 2) + (wl & 3)) << 7) + ((q ^ f) << 4);
            GLOAD16(psrc + goff, (char*)tk + ((size_t)(it * 512 + w8 * 64) << 4));
        }
    }
    __syncthreads();

    // ---- bmm: wave handles patches gxl = w8*2, w8*2+1
    {
        int p = l & 15, hi = l >> 4;
        for (int rnd = 0; rnd < 2; ++rnd) {
            const float* gbase = ln_g + rnd * 64;
            const float* bbase = ln_b + rnd * 64;
            float4 g0 = *(const float4*)&gbase[hi * 8];
            float4 g1 = *(const float4*)&gbase[hi * 8 + 4];
            float4 g2 = *(const float4*)&gbase[32 + hi * 8];
            float4 g3 = *(const float4*)&gbase[32 + hi * 8 + 4];
            float4 e0 = *(const float4*)&bbase[hi * 8];
            float4 e1 = *(const float4*)&bbase[hi * 8 + 4];
            float4 e2 = *(const float4*)&bbase[32 + hi * 8];
            float4 e3 = *(const float4*)&bbase[32 + hi * 8 + 4];
            float gA[8] = {g0.x, g0.y, g0.z, g0.w, g1.x, g1.y, g1.z, g1.w};
            float gB[8] = {g2.x, g2.y, g2.z, g2.w, g3.x, g3.y, g3.z, g3.w};
            float eA[8] = {e0.x, e0.y, e0.z, e0.w, e1.x, e1.y, e1.z, e1.w};
            float eB[8] = {e2.x, e2.y, e2.z, e2.w, e3.x, e3.y, e3.z, e3.w};
            #pragma unroll
            for (int gg = 0; gg < 2; ++gg) {
                int gxl = (w8 << 1) + gg;
                int nw = (gy << 5) + (half << 4) + gxl;
                const __hip_bfloat16* wrow = wgt_all + ((size_t)rnd << 22) + ((size_t)nw << 12);
                const float* brow = bias_all + ((size_t)rnd << 16) + ((size_t)nw << 6);
                int wl = (gxl << 2) + (p & 3);
                int py = p >> 2;
                int r = (py << 6) + wl;
                int f = (py + (p & 3) + ((gxl & 1) << 2)) & 7;
                char* trow = (char*)tk + r * 128;
                short8v aA = *(const short8v*)(trow + ((hi ^ f) << 4));
                short8v aB = *(const short8v*)(trow + (((4 + hi) ^ f) << 4));
                unsigned long long res[4];
                #pragma unroll
                for (int ib = 0; ib < 4; ++ib) {
                    int i0 = (ib << 4) + (hi << 2);
                    res[ib] = *(const unsigned long long*)(trow + (((i0 >> 3) ^ f) << 4) + ((i0 & 7) << 1));
                }
                float va[8], vb[8];
                float s = 0.f, s2 = 0.f;
                #pragma unroll
                for (int e = 0; e < 8; ++e) {
                    va[e] = bf2f(aA[e]); vb[e] = bf2f(aB[e]);
                    s += va[e] + vb[e];
                    s2 += va[e] * va[e] + vb[e] * vb[e];
                }
                s += __shfl_xor(s, 16); s2 += __shfl_xor(s2, 16);
                s += __shfl_xor(s, 32); s2 += __shfl_xor(s2, 32);
                float mean = s * (1.f / 64.f);
                float var = s2 * (1.f / 64.f) - mean * mean;
                float rinv = rsqrtf(var + 1e-5f);
                short8v bf0, bf1;
                #pragma unroll
                for (int e = 0; e < 8; ++e) {
                    bf0[e] = bf16s((va[e] - mean) * rinv * gA[e] + eA[e]);
                    bf1[e] = bf16s((vb[e] - mean) * rinv * gB[e] + eB[e]);
                }
                short8v af[4][2];
                #pragma unroll
                for (int ib = 0; ib < 4; ++ib) {
                    af[ib][0] = *(const short8v*)&wrow[((ib * 16 + p) << 6) + hi * 8];
                    af[ib][1] = *(const short8v*)&wrow[((ib * 16 + p) << 6) + 32 + hi * 8];
                }
                f32x4 acc[4] = {};
                #pragma unroll
                for (int ib = 0; ib < 4; ++ib) {
                    acc[ib] = __builtin_amdgcn_mfma_f32_16x16x32_bf16(af[ib][0], bf0, acc[ib], 0, 0, 0);
                    acc[ib] = __builtin_amdgcn_mfma_f32_16x16x32_bf16(af[ib][1], bf1, acc[ib], 0, 0, 0);
                }
                #pragma unroll
                for (int ib = 0; ib < 4; ++ib) {
                    int i0 = (ib << 4) + (hi << 2);
                    float4 bsv = *(const float4*)&brow[i0];
                    float ba[4] = {bsv.x, bsv.y, bsv.z, bsv.w};
                    union { unsigned short s[4]; unsigned long long u; } pk;
                    #pragma unroll
                    for (int rr2 = 0; rr2 < 4; ++rr2) {
                        float rv = bf2f((short)((res[ib] >> (16 * rr2)) & 0xffff));
                        pk.s[rr2] = bf16u(acc[ib][rr2] + ba[rr2] + rv);
                    }
                    *(unsigned long long*)(trow + (((i0 >> 3) ^ f) << 4) + ((i0 & 7) << 1)) = pk.u;
                }
            }
            __syncthreads();
        }
    }

    // ---- conv: wave w8 -> (py = w8>>1, oc-half wvo = w8&1); 2 oc sub-passes.
    // Conv-weight A-fragments read straight from cwt_g (global, L2 broadcast).
    {
        int py = w8 >> 1, wvo = w8 & 1;
        int lrow = l & 15, lhi = l >> 4;
        int hh = (gy << 2) + py;
        const char* cwg = (const char*)cwt_g;
        #pragma unroll
        for (int ih = 0; ih < 2; ++ih) {
            f32x4 acc[4][4] = {};
            #pragma unroll
            for (int ks = 0; ks < 2; ++ks) {
                int q = (ks << 2) + lhi;
                short8v a[4], bb[4];
                #pragma unroll
                for (int i = 0; i < 4; ++i) {
                    int ocr = wvo * 128 + (ih * 4 + i) * 16 + lrow;
                    a[i] = *(const short8v*)(cwg + ocr * 128 + ((q ^ (ocr & 7)) << 4));
                }
                #pragma unroll
                for (int j = 0; j < 4; ++j) {
                    int wl = (j << 4) + lrow;
                    int rr = (py << 6) + wl;
                    int ff = (py + (wl & 3) + (((wl >> 2) & 1) << 2)) & 7;
                    bb[j] = *(const short8v*)((const char*)tk + rr * 128 + ((q ^ ff) << 4));
                }
                #pragma unroll
                for (int i = 0; i < 4; ++i)
                    #pragma unroll
                    for (int j = 0; j < 4; ++j)
                        acc[i][j] = __builtin_amdgcn_mfma_f32_16x16x32_bf16(a[i], bb[j], acc[i][j], 0, 0, 0);
            }
            #pragma unroll
            for (int i = 0; i < 4; ++i) {
                int oc4 = wvo * 128 + (ih * 4 + i) * 16 + lhi * 4;
                int c = oc4 >> 2;
                float cb0 = cbl[oc4], cb1 = cbl[oc4 + 1];
                float cb2 = cbl[oc4 + 2], cb3 = cbl[oc4 + 3];
                float* row0 = out + (((size_t)b * 64 + c) * 256 + 2 * hh) * 256;
                float* row1 = row0 + 256;
                #pragma unroll
                for (int j = 0; j < 4; ++j) {
                    int ww = (half << 6) + (j << 4) + lrow;
                    ((float2*)row0)[ww] = make_float2(acc[i][j][0] + cb0, acc[i][j][1] + cb1);
                    ((float2*)row1)[ww] = make_float2(acc[i][j][2] + cb2, acc[i][j][3] + cb3);
                }
            }
        }
    }
}

// ---------------------------------------------------------------------------
extern "C" void kernel_launch(void* const* d_in, const int* in_sizes, int n_in,
                              void* d_out, int out_size, void* d_ws, size_t ws_size,
                              hipStream_t stream) {
    const float* x      = (const float*)d_in[0];
    const float* pixpos = (const float*)d_in[1];
    const float* ppe_w1 = (const float*)d_in[2];
    const float* ppe_b1 = (const float*)d_in[3];
    const float* ppe_w2 = (const float*)d_in[4];
    const float* ppe_b2 = (const float*)d_in[5];
    const float* ln_g   = (const float*)d_in[6];
    const float* ln_b   = (const float*)d_in[7];
    const float* wn_w1  = (const float*)d_in[8];
    const float* wn_b1  = (const float*)d_in[9];
    const float* wn_w2  = (const float*)d_in[10];
    const float* wn_b2  = (const float*)d_in[11];
    const float* bn_w1  = (const float*)d_in[12];
    const float* bn_b1  = (const float*)d_in[13];
    const float* bn_w2  = (const float*)d_in[14];
    const float* bn_b2  = (const float*)d_in[15];
    const float* conv_w = (const float*)d_in[16];
    const float* conv_b = (const float*)d_in[17];
    float* out = (float*)d_out;

    char* wsb = (char*)d_ws;
    __hip_bfloat16* procb   = (__hip_bfloat16*)wsb; wsb += (size_t)NPAT * 1024 * 2;     // 16 MB
    __hip_bfloat16* wgt_all = (__hip_bfloat16*)wsb; wsb += (size_t)2 * NPER * 4096 * 2; // 16 MB
    __hip_bfloat16* h1      = (__hip_bfloat16*)wsb; wsb += (size_t)2 * NPER * 256 * 2;  //  1 MB
    __hip_bfloat16* w2t     = (__hip_bfloat16*)wsb; wsb += (size_t)2 * 4096 * 256 * 2;  //  4 MB
    float* bias             = (float*)wsb;          wsb += (size_t)2 * NPER * 64 * 4;   // 512 KB
    __hip_bfloat16* summ    = (__hip_bfloat16*)wsb; wsb += (size_t)NPER * 64 * 2;       // 128 KB
    __hip_bfloat16* w1t     = (__hip_bfloat16*)wsb; wsb += (size_t)2 * 512 * 64 * 2;    // 128 KB
    __hip_bfloat16* w2bt    = (__hip_bfloat16*)wsb; wsb += (size_t)2 * 64 * 256 * 2;    //  64 KB
    __hip_bfloat16* cwt_g   = (__hip_bfloat16*)wsb;                                     //  32 KB

    k_setup<<<2240, 256, 0, stream>>>(x, procb, pixpos, ppe_w1, ppe_b1, ppe_w2, ppe_b2,
                                      summ, wn_w2, conv_w, wn_w1, bn_w1, bn_w2,
                                      w2t, cwt_g, w1t, w2bt);
    k_mlp_mfma<<<64, 256, 0, stream>>>(summ, w1t, wn_b1, bn_b1, w2bt, bn_b2, h1, bias);
    k_wgt_mfma<<<512, 256, 0, stream>>>(h1, w2t, wn_b2, wgt_all);
    k_strip<<<512, 512, 0, stream>>>(procb, wgt_all, bias, ln_g, ln_b,
                                     cwt_g, conv_b, out);
}

// Round 14
// 78.944 us; speedup vs baseline: 1.2494x; 1.0864x over previous
//
#include <hip/hip_runtime.h>
#include <hip/hip_bf16.h>

// Problem constants
constexpr int NPAT = 8192;     // B*PH*PW = 8*32*32
constexpr int NPER = 1024;     // coords period: summary/h1/bias/wgt repeat every 1024

typedef __attribute__((ext_vector_type(8))) short short8v;   // 8 bf16
typedef __attribute__((ext_vector_type(4))) float f32x4;

#define GLOAD16(g, l) __builtin_amdgcn_global_load_lds( \
    (const __attribute__((address_space(1))) void*)(g), \
    (__attribute__((address_space(3))) void*)(l), 16, 0, 0)

__device__ inline short bf16s(float f) {
    __hip_bfloat16 h = __float2bfloat16(f);
    return *reinterpret_cast<short*>(&h);
}
__device__ inline unsigned short bf16u(float f) {
    __hip_bfloat16 h = __float2bfloat16(f);
    return *reinterpret_cast<unsigned short*>(&h);
}
__device__ inline float bf2f(short s) {
    return __uint_as_float(((unsigned int)(unsigned short)s) << 16);
}

// ---------------------------------------------------------------------------
// K-SETUP: block-range dispatch.
//   [0,1024):    unfold x -> proc bf16
//   [1024,1280): summary for 1024 distinct coords (4 patches/block)
//   [1280,2240): weight prep (w2t transpose, cwt swizzle, w1t/w2bt)
__global__ __launch_bounds__(256) void k_setup(const float* __restrict__ x,
                                               __hip_bfloat16* __restrict__ proc,
                                               const float* __restrict__ pixpos,
                                               const float* __restrict__ pw1,
                                               const float* __restrict__ pb1,
                                               const float* __restrict__ pw2,
                                               const float* __restrict__ pb2,
                                               __hip_bfloat16* __restrict__ summ,
                                               const float* __restrict__ w2,
                                               const float* __restrict__ cw,
                                               const float* __restrict__ wn_w1,
                                               const float* __restrict__ bn_w1,
                                               const float* __restrict__ bn_w2,
                                               __hip_bfloat16* __restrict__ w2t,
                                               __hip_bfloat16* __restrict__ cwt_g,
                                               __hip_bfloat16* __restrict__ w1t,
                                               __hip_bfloat16* __restrict__ w2bt) {
    __shared__ __align__(16) char smem[33024];
    int bid = blockIdx.x;
    int t = threadIdx.x;
    if (bid < 1024) {
        // ---- extract
        float (*tile)[129] = (float(*)[129])smem;
        int b = bid >> 7, h = bid & 127;
        for (int it = 0; it < 8; ++it) {
            int idx = it * 256 + t;
            int c = idx >> 5, w4 = (idx & 31) * 4;
            float4 v = *(const float4*)&x[(((size_t)b * 64 + c) * 128 + h) * 128 + w4];
            tile[c][w4] = v.x; tile[c][w4 + 1] = v.y;
            tile[c][w4 + 2] = v.z; tile[c][w4 + 3] = v.w;
        }
        __syncthreads();
        int ny = (h >> 2) * 32, py = h & 3;
        for (int it = 0; it < 16; ++it) {
            int pw = it * 8 + (t >> 5);
            int cc = (t & 31) * 2;
            int n = (b << 10) + ny + (pw >> 2);
            int p = (py << 2) + (pw & 3);
            unsigned int u = (unsigned int)bf16u(tile[cc][pw]) |
                             ((unsigned int)bf16u(tile[cc + 1][pw]) << 16);
            *(unsigned int*)(proc + ((size_t)n << 10) + (p << 6) + cc) = u;
        }
    } else if (bid < 1280) {
        // ---- summary: wave w handles distinct-coord patch n in [0,1024)
        float (*hs)[260] = (float(*)[260])smem;
        int l = t & 63, w = t >> 6;
        int n = (bid - 1024) * 4 + w;
        float cy = (float)(n >> 5) * (1.f / 31.f);
        float cx = (float)(n & 31) * (1.f / 31.f);
        for (int k4 = 0; k4 < 4; ++k4) {
            int k = k4 * 64 + l;
            float v = cy * pw1[k] + cx * pw1[256 + k] + pb1[k];
            hs[w][k] = v / (1.f + __expf(-v));
        }
        float acc = pb2[l];
        for (int k = 0; k < 256; ++k) acc += hs[w][k] * pw2[k * 64 + l];
        float pm = 0.f;
        for (int p = 0; p < 16; ++p) pm += pixpos[p * 64 + l];
        summ[(size_t)n * 64 + l] = __float2bfloat16(acc + pm * (1.f / 16.f));
    } else {
        int pb = bid - 1280;
        if (pb < 512) {
            float (*tile)[65] = (float(*)[65])smem;
            int b = pb >> 8;
            int rem = pb & 255;
            int kt = rem >> 6, nt = rem & 63;
            const float* src = w2 + (size_t)b * 256 * 4096 + (size_t)(kt * 64) * 4096 + nt * 64;
            for (int it = 0; it < 16; ++it) {
                int idx = t + it * 256;
                int r = idx >> 6, c = idx & 63;
                tile[r][c] = src[(size_t)r * 4096 + c];
            }
            __syncthreads();
            __hip_bfloat16* dst = w2t + (size_t)b * 4096 * 256 + (size_t)(nt * 64) * 256 + kt * 64;
            for (int it = 0; it < 16; ++it) {
                int idx = t + it * 256;
                int rr = idx >> 6, cc = idx & 63;
                dst[rr * 256 + cc] = __float2bfloat16(tile[cc][rr]);
            }
        } else if (pb < 576) {
            int idx = (pb - 512) * 256 + t;
            int oc = idx >> 6, cc = idx & 63;
            float v = cw[cc * 256 + oc];
            int el = oc * 64 + (((cc >> 3) ^ (oc & 7)) << 3) + (cc & 7);
            cwt_g[el] = __float2bfloat16(v);
        } else {
            int idx = (pb - 576) * 256 + t;
            if (idx < 2 * 512 * 64) {
                int b = idx >> 15; int r = idx & 32767; int n = r >> 6; int k = r & 63;
                const float* src = (n < 256) ? wn_w1 : bn_w1;
                float v = src[((size_t)b * 64 + k) * 256 + (n & 255)];
                w1t[idx] = __float2bfloat16(v);
            } else {
                int j = idx - 2 * 512 * 64;
                int b = j >> 14; int r = j & 16383; int c = r >> 8; int k = r & 255;
                float v = bn_w2[((size_t)b * 256 + k) * 64 + c];
                w2bt[j] = __float2bfloat16(v);
            }
        }
    }
}

// ---------------------------------------------------------------------------
// K3 (MFMA): both hyper-blocks, 1024 distinct patches. 64 blocks, 32 patches each.
__global__ __launch_bounds__(256) void k_mlp_mfma(const __hip_bfloat16* __restrict__ summary,
                                                  const __hip_bfloat16* __restrict__ w1t_all,
                                                  const float* __restrict__ wn_b1,
                                                  const float* __restrict__ bn_b1,
                                                  const __hip_bfloat16* __restrict__ w2bt_all,
                                                  const float* __restrict__ bn_b2,
                                                  __hip_bfloat16* __restrict__ h1_all,
                                                  float* __restrict__ bias_all) {
    __shared__ short st[32 * 64];
    __shared__ short hb[32 * 256];
    int t = threadIdx.x;
    int l = t & 63, w = t >> 6;
    int bi = blockIdx.x;
    int i = bi >> 5;
    int m0 = (bi & 31) * 32;
    int lrow = l & 15, hi = l >> 4;

    const __hip_bfloat16* w1t = w1t_all + (size_t)i * 512 * 64;
    const __hip_bfloat16* w2bt = w2bt_all + (size_t)i * 64 * 256;
    const float* b1w = wn_b1 + i * 256;
    const float* b1b = bn_b1 + i * 256;
    const float* b2b = bn_b2 + i * 64;
    __hip_bfloat16* h1out = h1_all + (size_t)i * NPER * 256;
    float* biasout = bias_all + (size_t)i * NPER * 64;

    {
        int chunk = w * 64 + l;
        int m = chunk >> 3, q = chunk & 7;
        int gq = q ^ (m & 7);
        GLOAD16((const char*)(summary + ((size_t)(m0 + m) << 6) + (gq << 3)),
                (char*)st + (size_t)(w * 64) * 16);
    }
    __syncthreads();

    f32x4 acc[8][2] = {};
    for (int ks = 0; ks < 2; ++ks) {
        short8v a[8], bb[2];
        for (int ii = 0; ii < 8; ++ii) {
            int n = w * 128 + ii * 16 + lrow;
            a[ii] = *(const short8v*)&w1t[(size_t)n * 64 + ks * 32 + hi * 8];
        }
        for (int j = 0; j < 2; ++j) {
            int m = j * 16 + lrow;
            int kk = ks * 4 + hi;
            bb[j] = *(const short8v*)((const char*)st + m * 128 + ((kk ^ (m & 7)) << 4));
        }
        for (int ii = 0; ii < 8; ++ii)
            for (int j = 0; j < 2; ++j)
                acc[ii][j] = __builtin_amdgcn_mfma_f32_16x16x32_bf16(a[ii], bb[j], acc[ii][j], 0, 0, 0);
    }
    if (w < 2) {
        for (int ii = 0; ii < 8; ++ii) {
            int n0_ = w * 128 + ii * 16 + hi * 4;
            float4 bw = *(const float4*)&b1w[n0_];
            float bwa[4] = {bw.x, bw.y, bw.z, bw.w};
            for (int j = 0; j < 2; ++j) {
                union { unsigned short s[4]; unsigned long long u; } pk;
                for (int r = 0; r < 4; ++r) {
                    float z = acc[ii][j][r] + bwa[r];
                    pk.s[r] = bf16u(z / (1.f + __expf(-z)));
                }
                int m = m0 + j * 16 + lrow;
                *(unsigned long long*)&h1out[(size_t)m * 256 + n0_] = pk.u;
            }
        }
    } else {
        for (int ii = 0; ii < 8; ++ii) {
            int nb0 = (w - 2) * 128 + ii * 16 + hi * 4;
            float4 bw = *(const float4*)&b1b[nb0];
            float bwa[4] = {bw.x, bw.y, bw.z, bw.w};
            for (int j = 0; j < 2; ++j) {
                union { unsigned short s[4]; unsigned long long u; } pk;
                for (int r = 0; r < 4; ++r) {
                    float z = acc[ii][j][r] + bwa[r];
                    pk.s[r] = bf16u(z / (1.f + __expf(-z)));
                }
                int mloc = j * 16 + lrow;
                int qq = nb0 >> 3;
                *(unsigned long long*)((char*)hb + mloc * 512 +
                                       ((qq ^ (mloc & 7)) << 4) + ((nb0 & 7) << 1)) = pk.u;
            }
        }
    }
    __syncthreads();

    f32x4 acc2[2] = {};
    for (int ks = 0; ks < 8; ++ks) {
        short8v a2 = *(const short8v*)&w2bt[(size_t)(w * 16 + lrow) * 256 + ks * 32 + hi * 8];
        for (int j = 0; j < 2; ++j) {
            int ml = j * 16 + lrow;
            int kk = ks * 4 + hi;
            short8v b2f = *(const short8v*)((const char*)hb + ml * 512 + ((kk ^ (ml & 7)) << 4));
            acc2[j] = __builtin_amdgcn_mfma_f32_16x16x32_bf16(a2, b2f, acc2[j], 0, 0, 0);
        }
    }
    {
        int c0 = w * 16 + hi * 4;
        float4 bv = *(const float4*)&b2b[c0];
        for (int j = 0; j < 2; ++j) {
            int m = m0 + j * 16 + lrow;
            float4 o;
            o.x = acc2[j][0] + bv.x; o.y = acc2[j][1] + bv.y;
            o.z = acc2[j][2] + bv.z; o.w = acc2[j][3] + bv.w;
            *(float4*)&biasout[(size_t)m * 64 + c0] = o;
        }
    }
}

// ---------------------------------------------------------------------------
// K4: wgt GEMM for BOTH hyper-blocks. M=1024, N=4096, K=256 each.
__global__ __launch_bounds__(256) void k_wgt_mfma(const __hip_bfloat16* __restrict__ h1_all,
                                                  const __hip_bfloat16* __restrict__ w2t_all,
                                                  const float* __restrict__ b2_all,
                                                  __hip_bfloat16* __restrict__ wgt_all) {
    __shared__ short sm[2][128 * 68];
    int t = threadIdx.x;
    int l = t & 63, w = t >> 6;
    int i = blockIdx.x >> 8;
    int bid8 = blockIdx.x & 255;
    int mt = bid8 & 7, nt = bid8 >> 3;
    int m0 = mt << 7, n0 = nt << 7;
    int wr = w >> 1, wc = w & 1;
    int lrow = l & 15, hi = l >> 4;

    const __hip_bfloat16* h1 = h1_all + (size_t)i * NPER * 256;
    const __hip_bfloat16* w2t = w2t_all + (size_t)i * 4096 * 256;
    const float* b2 = b2_all + (size_t)i * 4096;
    __hip_bfloat16* wgt = wgt_all + ((size_t)i << 22);

    f32x4 acc[4][4] = {};

    const char* gA = (const char*)(h1 + (size_t)m0 * 256);
    const char* gB = (const char*)(w2t + (size_t)n0 * 256);

    for (int ks = 0; ks < 4; ++ks) {
        int k0 = ks * 64;
        #pragma unroll
        for (int it = 0; it < 4; ++it) {
            int c = it * 256 + t;
            int row = c >> 3, q = c & 7;
            size_t goff = ((size_t)row * 256 + k0 + ((q ^ (row & 7)) << 3)) * 2;
            size_t ldst = (size_t)(it * 256 + w * 64) * 16;
            GLOAD16(gA + goff, (char*)sm[0] + ldst);
            GLOAD16(gB + goff, (char*)sm[1] + ldst);
        }
        __syncthreads();
        #pragma unroll
        for (int kk = 0; kk < 2; ++kk) {
            int kq = kk * 4 + hi;
            short8v a[4], b[4];
            #pragma unroll
            for (int fi = 0; fi < 4; ++fi) {
                int row = wc * 64 + fi * 16 + lrow;
                a[fi] = *(const short8v*)((const char*)sm[1] + row * 128 + ((kq ^ (row & 7)) << 4));
            }
            #pragma unroll
            for (int fj = 0; fj < 4; ++fj) {
                int row = wr * 64 + fj * 16 + lrow;
                b[fj] = *(const short8v*)((const char*)sm[0] + row * 128 + ((kq ^ (row & 7)) << 4));
            }
            #pragma unroll
            for (int fi = 0; fi < 4; ++fi)
                #pragma unroll
                for (int fj = 0; fj < 4; ++fj)
                    acc[fi][fj] = __builtin_amdgcn_mfma_f32_16x16x32_bf16(a[fi], b[fj], acc[fi][fj], 0, 0, 0);
        }
        __syncthreads();
    }

    short* epi = (short*)sm;
    #pragma unroll
    for (int fi = 0; fi < 4; ++fi) {
        int nl = wc * 64 + fi * 16 + hi * 4;
        float4 bv = *(const float4*)&b2[n0 + nl];
        float bva[4] = {bv.x, bv.y, bv.z, bv.w};
        #pragma unroll
        for (int fj = 0; fj < 4; ++fj) {
            int m = wr * 64 + fj * 16 + lrow;
            union { unsigned short s[4]; unsigned long long u; } pk;
            #pragma unroll
            for (int r = 0; r < 4; ++r)
                pk.s[r] = bf16u(acc[fi][fj][r] + bva[r]);
            *(unsigned long long*)((char*)epi + (size_t)m * 272 + nl * 2) = pk.u;
        }
    }
    __syncthreads();
    #pragma unroll
    for (int pass = 0; pass < 8; ++pass) {
        int row = pass * 16 + (t >> 4);
        int c8 = (t & 15) * 8;
        uint4 v = *(const uint4*)((const char*)epi + (size_t)row * 272 + c8 * 2);
        *(uint4*)&wgt[(size_t)(m0 + row) * 4096 + n0 + c8] = v;
    }
}

// ---------------------------------------------------------------------------
// K-STRIP: fused bmm(x2) + conv + pixel shuffle. HALF-strips for 2x grid.
// Block = (b, gy, quarter): 8 patches (gx = quarter*8..+8), 512 threads (8 waves).
// LDS token tile tk[r = py*32 + wl][cc 64] bf16, wl in [0,32),
// XOR-swizzle f(r) = (py + (wl&3) + 4*((wl>>2)&1)) & 7 (same formula as r10).
__global__ __launch_bounds__(512) void k_strip(const __hip_bfloat16* __restrict__ proc,
                                               const __hip_bfloat16* __restrict__ wgt_all,
                                               const float* __restrict__ bias_all,
                                               const float* __restrict__ ln_g,
                                               const float* __restrict__ ln_b,
                                               const __hip_bfloat16* __restrict__ cwt_g,
                                               const float* __restrict__ cb,
                                               float* __restrict__ out) {
    __shared__ short tk[128 * 64];    // 16 KB
    __shared__ short cwt[256 * 64];   // 32 KB
    __shared__ float cbl[256];
    int t = threadIdx.x;
    int l = t & 63, w8 = t >> 6;
    int bid = blockIdx.x;
    int quarter = bid & 3, gy = (bid >> 2) & 31, b = bid >> 7;
    int nbase = (b << 10) + (gy << 5) + (quarter << 3);

    // ---- stage conv weights (2048 chunks)
    for (int it = 0; it < 4; ++it) {
        int cid0 = it * 512 + w8 * 64;
        GLOAD16((const char*)cwt_g + ((size_t)(cid0 + l) << 4),
                (char*)cwt + ((size_t)cid0 << 4));
    }
    if (t < 256) cbl[t] = cb[t];
    // ---- stage token tile (1024 chunks), pre-swizzled global source
    {
        const char* psrc = (const char*)(proc + ((size_t)nbase << 10));
        #pragma unroll
        for (int it = 0; it < 2; ++it) {
            int c = it * 512 + t;
            int r = c >> 3, q = c & 7;
            int wl = r & 31, py = r >> 5;
            int f = (py + (wl & 3) + (((wl >> 2) & 1) << 2)) & 7;
            int goff = ((wl >> 2) << 11) + (((py << 2) + (wl & 3)) << 7) + ((q ^ f) << 4);
            GLOAD16(psrc + goff, (char*)tk + ((size_t)(it * 512 + w8 * 64) << 4));
        }
    }
    __syncthreads();

    // ---- bmm: wave w8 handles patch gxl = w8
    {
        int p = l & 15, hi = l >> 4;
        int gxl = w8;
        for (int rnd = 0; rnd < 2; ++rnd) {
            const float* gbase = ln_g + rnd * 64;
            const float* bbase = ln_b + rnd * 64;
            float4 g0 = *(const float4*)&gbase[hi * 8];
            float4 g1 = *(const float4*)&gbase[hi * 8 + 4];
            float4 g2 = *(const float4*)&gbase[32 + hi * 8];
            float4 g3 = *(const float4*)&gbase[32 + hi * 8 + 4];
            float4 e0 = *(const float4*)&bbase[hi * 8];
            float4 e1 = *(const float4*)&bbase[hi * 8 + 4];
            float4 e2 = *(const float4*)&bbase[32 + hi * 8];
            float4 e3 = *(const float4*)&bbase[32 + hi * 8 + 4];
            float gA[8] = {g0.x, g0.y, g0.z, g0.w, g1.x, g1.y, g1.z, g1.w};
            float gB[8] = {g2.x, g2.y, g2.z, g2.w, g3.x, g3.y, g3.z, g3.w};
            float eA[8] = {e0.x, e0.y, e0.z, e0.w, e1.x, e1.y, e1.z, e1.w};
            float eB[8] = {e2.x, e2.y, e2.z, e2.w, e3.x, e3.y, e3.z, e3.w};
            {
                int nw = (gy << 5) + (quarter << 3) + gxl;
                const __hip_bfloat16* wrow = wgt_all + ((size_t)rnd << 22) + ((size_t)nw << 12);
                const float* brow = bias_all + ((size_t)rnd << 16) + ((size_t)nw << 6);
                int wl = (gxl << 2) + (p & 3);
                int py = p >> 2;
                int r = (py << 5) + wl;
                int f = (py + (p & 3) + ((gxl & 1) << 2)) & 7;
                char* trow = (char*)tk + r * 128;
                short8v aA = *(const short8v*)(trow + ((hi ^ f) << 4));
                short8v aB = *(const short8v*)(trow + (((4 + hi) ^ f) << 4));
                unsigned long long res[4];
                #pragma unroll
                for (int ib = 0; ib < 4; ++ib) {
                    int i0 = (ib << 4) + (hi << 2);
                    res[ib] = *(const unsigned long long*)(trow + (((i0 >> 3) ^ f) << 4) + ((i0 & 7) << 1));
                }
                float va[8], vb[8];
                float s = 0.f, s2 = 0.f;
                #pragma unroll
                for (int e = 0; e < 8; ++e) {
                    va[e] = bf2f(aA[e]); vb[e] = bf2f(aB[e]);
                    s += va[e] + vb[e];
                    s2 += va[e] * va[e] + vb[e] * vb[e];
                }
                s += __shfl_xor(s, 16); s2 += __shfl_xor(s2, 16);
                s += __shfl_xor(s, 32); s2 += __shfl_xor(s2, 32);
                float mean = s * (1.f / 64.f);
                float var = s2 * (1.f / 64.f) - mean * mean;
                float rinv = rsqrtf(var + 1e-5f);
                short8v bf0, bf1;
                #pragma unroll
                for (int e = 0; e < 8; ++e) {
                    bf0[e] = bf16s((va[e] - mean) * rinv * gA[e] + eA[e]);
                    bf1[e] = bf16s((vb[e] - mean) * rinv * gB[e] + eB[e]);
                }
                short8v af[4][2];
                #pragma unroll
                for (int ib = 0; ib < 4; ++ib) {
                    af[ib][0] = *(const short8v*)&wrow[((ib * 16 + p) << 6) + hi * 8];
                    af[ib][1] = *(const short8v*)&wrow[((ib * 16 + p) << 6) + 32 + hi * 8];
                }
                f32x4 acc[4] = {};
                #pragma unroll
                for (int ib = 0; ib < 4; ++ib) {
                    acc[ib] = __builtin_amdgcn_mfma_f32_16x16x32_bf16(af[ib][0], bf0, acc[ib], 0, 0, 0);
                    acc[ib] = __builtin_amdgcn_mfma_f32_16x16x32_bf16(af[ib][1], bf1, acc[ib], 0, 0, 0);
                }
                #pragma unroll
                for (int ib = 0; ib < 4; ++ib) {
                    int i0 = (ib << 4) + (hi << 2);
                    float4 bsv = *(const float4*)&brow[i0];
                    float ba[4] = {bsv.x, bsv.y, bsv.z, bsv.w};
                    union { unsigned short s[4]; unsigned long long u; } pk;
                    #pragma unroll
                    for (int rr2 = 0; rr2 < 4; ++rr2) {
                        float rv = bf2f((short)((res[ib] >> (16 * rr2)) & 0xffff));
                        pk.s[rr2] = bf16u(acc[ib][rr2] + ba[rr2] + rv);
                    }
                    *(unsigned long long*)(trow + (((i0 >> 3) ^ f) << 4) + ((i0 & 7) << 1)) = pk.u;
                }
            }
            __syncthreads();
        }
    }

    // ---- conv: wave w8 -> (py = w8>>1, oc-half wvo = w8&1); 2 oc sub-passes
    {
        int py = w8 >> 1, wvo = w8 & 1;
        int lrow = l & 15, lhi = l >> 4;
        int hh = (gy << 2) + py;
        #pragma unroll
        for (int ih = 0; ih < 2; ++ih) {
            f32x4 acc[4][2] = {};
            #pragma unroll
            for (int ks = 0; ks < 2; ++ks) {
                int q = (ks << 2) + lhi;
                short8v a[4], bb[2];
                #pragma unroll
                for (int i = 0; i < 4; ++i) {
                    int ocr = wvo * 128 + (ih * 4 + i) * 16 + lrow;
                    a[i] = *(const short8v*)((const char*)cwt + ocr * 128 + ((q ^ (ocr & 7)) << 4));
                }
                #pragma unroll
                for (int j = 0; j < 2; ++j) {
                    int wl = (j << 4) + lrow;
                    int rr = (py << 5) + wl;
                    int ff = (py + (wl & 3) + (((wl >> 2) & 1) << 2)) & 7;
                    bb[j] = *(const short8v*)((const char*)tk + rr * 128 + ((q ^ ff) << 4));
                }
                #pragma unroll
                for (int i = 0; i < 4; ++i)
                    #pragma unroll
                    for (int j = 0; j < 2; ++j)
                        acc[i][j] = __builtin_amdgcn_mfma_f32_16x16x32_bf16(a[i], bb[j], acc[i][j], 0, 0, 0);
            }
            #pragma unroll
            for (int i = 0; i < 4; ++i) {
                int oc4 = wvo * 128 + (ih * 4 + i) * 16 + lhi * 4;
                int c = oc4 >> 2;
                float cb0 = cbl[oc4], cb1 = cbl[oc4 + 1];
                float cb2 = cbl[oc4 + 2], cb3 = cbl[oc4 + 3];
                float* row0 = out + (((size_t)b * 64 + c) * 256 + 2 * hh) * 256;
                float* row1 = row0 + 256;
                #pragma unroll
                for (int j = 0; j < 2; ++j) {
                    int ww = (quarter << 5) + (j << 4) + lrow;
                    ((float2*)row0)[ww] = make_float2(acc[i][j][0] + cb0, acc[i][j][1] + cb1);
                    ((float2*)row1)[ww] = make_float2(acc[i][j][2] + cb2, acc[i][j][3] + cb3);
                }
            }
        }
    }
}

// ---------------------------------------------------------------------------
extern "C" void kernel_launch(void* const* d_in, const int* in_sizes, int n_in,
                              void* d_out, int out_size, void* d_ws, size_t ws_size,
                              hipStream_t stream) {
    const float* x      = (const float*)d_in[0];
    const float* pixpos = (const float*)d_in[1];
    const float* ppe_w1 = (const float*)d_in[2];
    const float* ppe_b1 = (const float*)d_in[3];
    const float* ppe_w2 = (const float*)d_in[4];
    const float* ppe_b2 = (const float*)d_in[5];
    const float* ln_g   = (const float*)d_in[6];
    const float* ln_b   = (const float*)d_in[7];
    const float* wn_w1  = (const float*)d_in[8];
    const float* wn_b1  = (const float*)d_in[9];
    const float* wn_w2  = (const float*)d_in[10];
    const float* wn_b2  = (const float*)d_in[11];
    const float* bn_w1  = (const float*)d_in[12];
    const float* bn_b1  = (const float*)d_in[13];
    const float* bn_w2  = (const float*)d_in[14];
    const float* bn_b2  = (const float*)d_in[15];
    const float* conv_w = (const float*)d_in[16];
    const float* conv_b = (const float*)d_in[17];
    float* out = (float*)d_out;

    char* wsb = (char*)d_ws;
    __hip_bfloat16* procb   = (__hip_bfloat16*)wsb; wsb += (size_t)NPAT * 1024 * 2;     // 16 MB
    __hip_bfloat16* wgt_all = (__hip_bfloat16*)wsb; wsb += (size_t)2 * NPER * 4096 * 2; // 16 MB
    __hip_bfloat16* h1      = (__hip_bfloat16*)wsb; wsb += (size_t)2 * NPER * 256 * 2;  //  1 MB
    __hip_bfloat16* w2t     = (__hip_bfloat16*)wsb; wsb += (size_t)2 * 4096 * 256 * 2;  //  4 MB
    float* bias             = (float*)wsb;          wsb += (size_t)2 * NPER * 64 * 4;   // 512 KB
    __hip_bfloat16* summ    = (__hip_bfloat16*)wsb; wsb += (size_t)NPER * 64 * 2;       // 128 KB
    __hip_bfloat16* w1t     = (__hip_bfloat16*)wsb; wsb += (size_t)2 * 512 * 64 * 2;    // 128 KB
    __hip_bfloat16* w2bt    = (__hip_bfloat16*)wsb; wsb += (size_t)2 * 64 * 256 * 2;    //  64 KB
    __hip_bfloat16* cwt_g   = (__hip_bfloat16*)wsb;                                     //  32 KB

    k_setup<<<2240, 256, 0, stream>>>(x, procb, pixpos, ppe_w1, ppe_b1, ppe_w2, ppe_b2,
                                      summ, wn_w2, conv_w, wn_w1, bn_w1, bn_w2,
                                      w2t, cwt_g, w1t, w2bt);
    k_mlp_mfma<<<64, 256, 0, stream>>>(summ, w1t, wn_b1, bn_b1, w2bt, bn_b2, h1, bias);
    k_wgt_mfma<<<512, 256, 0, stream>>>(h1, w2t, wn_b2, wgt_all);
    k_strip<<<1024, 512, 0, stream>>>(procb, wgt_all, bias, ln_g, ln_b,
                                      cwt_g, conv_b, out);
}